// Round 8
// baseline (221.206 us; speedup 1.0000x reference)
//
#include <hip/hip_runtime.h>
#include <hip/hip_bf16.h>
#include <math.h>

#define Bb 2
#define Tt 2048
#define Cc 1024
#define Hh 16
#define HDd 64
#define QSCALE 0.18033688011112042f   // 0.125 * log2(e): folds softmax scale + exp->exp2

typedef __attribute__((ext_vector_type(8))) short short8;
typedef __attribute__((ext_vector_type(4))) short short4v;
typedef __attribute__((ext_vector_type(4))) float f32x4;

#if defined(__has_builtin)
#if __has_builtin(__builtin_amdgcn_global_load_lds)
#define USE_GLL 1
#endif
#endif
#define AS_GLOBAL __attribute__((address_space(1)))
#define AS_LDS    __attribute__((address_space(3)))

__device__ __forceinline__ float bf2f(unsigned short u){
  union { unsigned int i; float f; } v; v.i = ((unsigned int)u)<<16; return v.f;
}
__device__ __forceinline__ unsigned short f2bf(float f){
  union { float f; unsigned int i; } v; v.f = f;
  unsigned int x = v.i;
  return (unsigned short)((x + 0x7fffu + ((x>>16)&1u)) >> 16);
}
__device__ __forceinline__ unsigned int cvtpk_bf16(float lo, float hi){
  unsigned int r;
  asm("v_cvt_pk_bf16_f32 %0, %1, %2" : "=v"(r) : "v"(lo), "v"(hi));
  return r;
}
__device__ __forceinline__ float exp2fast(float x){
  float r; asm("v_exp_f32 %0, %1" : "=v"(r) : "v"(x)); return r;
}
__device__ __forceinline__ f32x4 mfma16(short4v a, short4v b, f32x4 c){
#if defined(__has_builtin)
#if __has_builtin(__builtin_amdgcn_mfma_f32_16x16x16_bf16)
  return __builtin_amdgcn_mfma_f32_16x16x16_bf16(a, b, c, 0, 0, 0);
#elif __has_builtin(__builtin_amdgcn_mfma_f32_16x16x16bf16_1k)
  return __builtin_amdgcn_mfma_f32_16x16x16bf16_1k(a, b, c, 0, 0, 0);
#else
  asm("v_mfma_f32_16x16x16_bf16 %0, %1, %2, %3" : "=v"(c) : "v"(a), "v"(b), "0"(c));
  return c;
#endif
#else
  asm("v_mfma_f32_16x16x16_bf16 %0, %1, %2, %3" : "=v"(c) : "v"(a), "v"(b), "0"(c));
  return c;
#endif
}

// ---------------- fp32 -> bf16 convert (vector) ----------------
__global__ __launch_bounds__(256) void k_f2b(const float* __restrict__ in,
                                             unsigned short* __restrict__ out, int n){
  int i = (blockIdx.x*256 + threadIdx.x)*4;
  if (i >= n) return;
  float4 v = *(const float4*)(in + i);
  unsigned long long p = (unsigned long long)f2bf(v.x)
                       | ((unsigned long long)f2bf(v.y)<<16)
                       | ((unsigned long long)f2bf(v.z)<<32)
                       | ((unsigned long long)f2bf(v.w)<<48);
  *(unsigned long long*)(out + i) = p;
}

// ---------------- transpose + convert: W[K][N] f32 -> Wt[N][K] bf16 ----------------
__global__ __launch_bounds__(256) void k_transpose_f2b(const float* __restrict__ in,
                                                       unsigned short* __restrict__ out,
                                                       int K, int N){
  __shared__ float tile[32][33];
  int kb = blockIdx.y*32, nb = blockIdx.x*32;
  int tx = threadIdx.x, ty = threadIdx.y; // (32, 8)
  #pragma unroll
  for (int i=0;i<4;i++)
    tile[ty+i*8][tx] = in[(size_t)(kb+ty+i*8)*N + nb + tx];
  __syncthreads();
  #pragma unroll
  for (int i=0;i<4;i++)
    out[(size_t)(nb+ty+i*8)*K + kb + tx] = f2bf(tile[tx][ty+i*8]);
}

// ---------------- scan: global token counts -> per-batch cumulative rotations ----------------
__global__ __launch_bounds__(1024) void k_scan(const int* __restrict__ tok,
                                               float* __restrict__ rot){
  __shared__ int cnt[2048];
  __shared__ float vals[2048];
  __shared__ float psum[1024];
  int b = blockIdx.x;
  int tid = threadIdx.x;
  cnt[tid] = 0; cnt[tid+1024] = 0;
  __syncthreads();
  // reference's fancy-indexing scatters ALL batches' tokens into every batch's counts
  for (int i = tid; i < Bb*Tt; i += 1024) atomicAdd(&cnt[tok[i]], 1);
  __syncthreads();
  for (int i = tid; i < Tt; i += 1024){
    int idx = tok[b*Tt + i];
    vals[i] = 1.0f / ((float)cnt[idx] + 1e-10f);
  }
  __syncthreads();
  float s0 = vals[2*tid], s1 = vals[2*tid+1];
  psum[tid] = s0 + s1;
  __syncthreads();
  for (int off=1; off<1024; off<<=1){
    float add = (tid>=off) ? psum[tid-off] : 0.0f;
    __syncthreads();
    psum[tid] += add;
    __syncthreads();
  }
  float base = (tid>0) ? psum[tid-1] : 0.0f;
  rot[b*Tt + 2*tid]   = base + s0;
  rot[b*Tt + 2*tid+1] = base + s0 + s1;
}

// ---------------- cos/sin tables from rotations ----------------
__global__ __launch_bounds__(256) void k_tables(const float* __restrict__ rot,
                                                float* __restrict__ cos_t,
                                                float* __restrict__ sin_t){
  int i = blockIdx.x*256 + threadIdx.x;   // over Bb*Tt*32
  int j = i & 31;
  int bt = i >> 5;
  float invf = exp2f(-(float)j * 0.4152410118609203f);  // 10000^(-j/32)
  float ang = rot[bt] * invf;
  cos_t[i] = cosf(ang);
  sin_t[i] = sinf(ang);
}

// ---------------- fused QKV GEMM: qkv = x@W + b, then rope/overwrite/scale ----------------
// 128x128 tile. Epilogue per output type (block-uniform): Q/K get rotate-half rope
// (partner acc[m][n^2], thread-local) + last-dim overwrite; V gets exp(cum) scale
// + LDS-bounce transpose to VT. cos/sin cached in LDS (union with staging buffers).
__global__ __launch_bounds__(256) void k_gemmQKV(const unsigned short* __restrict__ A,
                                                 const unsigned short* __restrict__ Bt,
                                                 const float* __restrict__ bias,
                                                 const float* __restrict__ cos_t,
                                                 const float* __restrict__ sin_t,
                                                 const float* __restrict__ cum,
                                                 unsigned short* __restrict__ Qo,
                                                 unsigned short* __restrict__ Ko,
                                                 unsigned short* __restrict__ VTo){
  __shared__ union {
    unsigned short ab[2][128][32];   // staging: [0]=A, [1]=B
    unsigned short v[2][128][68];    // V transpose bounce (pad 68: lhi groups 8 banks apart)
    float cs[2][128][36];            // cos/sin cache (pad 36: float4-aligned, 2-way banks)
  } sm;
  const int K = 1024, N = 3072;
  int mb = blockIdx.y*128, nb = blockIdx.x*128;
  int tid = threadIdx.x;
  int wave = tid>>6, lane = tid&63;
  int wr = wave>>1, wc = wave&1;
  int lrow = lane&15, lhi = lane>>4;
  f32x4 acc[4][4] = {};
  int r0 = tid>>2;
  int c0 = (tid&3)*8;
  const unsigned short* Arow0 = A  + (size_t)(mb + r0)*K      + c0;
  const unsigned short* Arow1 = A  + (size_t)(mb + r0 + 64)*K + c0;
  const unsigned short* Brow0 = Bt + (size_t)(nb + r0)*K      + c0;
  const unsigned short* Brow1 = Bt + (size_t)(nb + r0 + 64)*K + c0;
#ifdef USE_GLL
  for (int kb=0; kb<K; kb+=32){
    __builtin_amdgcn_global_load_lds((const AS_GLOBAL void*)(Arow0 + kb),
                                     (AS_LDS void*)&sm.ab[0][r0][c0],    16, 0, 0);
    __builtin_amdgcn_global_load_lds((const AS_GLOBAL void*)(Arow1 + kb),
                                     (AS_LDS void*)&sm.ab[0][r0+64][c0], 16, 0, 0);
    __builtin_amdgcn_global_load_lds((const AS_GLOBAL void*)(Brow0 + kb),
                                     (AS_LDS void*)&sm.ab[1][r0][c0],    16, 0, 0);
    __builtin_amdgcn_global_load_lds((const AS_GLOBAL void*)(Brow1 + kb),
                                     (AS_LDS void*)&sm.ab[1][r0+64][c0], 16, 0, 0);
    __syncthreads();
    short8 af[4], bf[4];
    #pragma unroll
    for (int m=0;m<4;m++) af[m] = *(const short8*)&sm.ab[0][64*wr + 16*m + lrow][8*lhi];
    #pragma unroll
    for (int n=0;n<4;n++) bf[n] = *(const short8*)&sm.ab[1][64*wc + 16*n + lrow][8*lhi];
    #pragma unroll
    for (int m=0;m<4;m++)
      #pragma unroll
      for (int n=0;n<4;n++)
        acc[m][n] = __builtin_amdgcn_mfma_f32_16x16x32_bf16(af[m], bf[n], acc[m][n], 0,0,0);
    __syncthreads();
  }
#else
  for (int kb=0; kb<K; kb+=32){
    int4 a0 = *(const int4*)(Arow0 + kb);
    int4 a1 = *(const int4*)(Arow1 + kb);
    int4 b0 = *(const int4*)(Brow0 + kb);
    int4 b1 = *(const int4*)(Brow1 + kb);
    __syncthreads();
    *(int4*)&sm.ab[0][r0][c0]    = a0;
    *(int4*)&sm.ab[0][r0+64][c0] = a1;
    *(int4*)&sm.ab[1][r0][c0]    = b0;
    *(int4*)&sm.ab[1][r0+64][c0] = b1;
    __syncthreads();
    short8 af[4], bf[4];
    #pragma unroll
    for (int m=0;m<4;m++) af[m] = *(const short8*)&sm.ab[0][64*wr + 16*m + lrow][8*lhi];
    #pragma unroll
    for (int n=0;n<4;n++) bf[n] = *(const short8*)&sm.ab[1][64*wc + 16*n + lrow][8*lhi];
    #pragma unroll
    for (int m=0;m<4;m++)
      #pragma unroll
      for (int n=0;n<4;n++)
        acc[m][n] = __builtin_amdgcn_mfma_f32_16x16x32_bf16(af[m], bf[n], acc[m][n], 0,0,0);
  }
#endif
  __syncthreads();                           // staging LDS dead; safe to repurpose
  int type = nb >> 10;                       // 0=Q 1=K 2=V (1024-boundaries are 128-aligned)
  int h0 = (nb >> 6) & 15;
  int h  = h0 + wc;                          // wave's head (64-col span = 1 head)
  int b_ = mb >> 11;
  int tb_ = mb & 2047;
  float bz[4];
  #pragma unroll
  for (int n=0;n<4;n++) bz[n] = bias[nb + 64*wc + 16*n + lrow];

  if (type < 2){
    // cache cos/sin rows for this block's 128 rows
    #pragma unroll
    for (int i=0;i<4;i++){
      int idx = i*256 + tid;
      int rw = idx >> 3, j4 = (idx & 7) << 2;
      *(float4*)&sm.cs[0][rw][j4] = *(const float4*)(cos_t + (size_t)(mb+rw)*32 + j4);
      *(float4*)&sm.cs[1][rw][j4] = *(const float4*)(sin_t + (size_t)(mb+rw)*32 + j4);
    }
    __syncthreads();
    unsigned short* dst = (type==0) ? Qo : Ko;
    #pragma unroll
    for (int m=0;m<4;m++)
      #pragma unroll
      for (int q=0;q<4;q++){
        int rl = 64*wr + 16*m + 4*lhi + q;
        int row = mb + rl;
        float c0v = sm.cs[0][rl][lrow],    s0v = sm.cs[1][rl][lrow];
        float c1v = sm.cs[0][rl][16+lrow], s1v = sm.cs[1][rl][16+lrow];
        float a0 = acc[m][0][q] + bz[0];   // d = lrow
        float a1 = acc[m][1][q] + bz[1];   // d = 16+lrow
        float a2 = acc[m][2][q] + bz[2];   // d = 32+lrow
        float a3 = acc[m][3][q] + bz[3];   // d = 48+lrow
        float r0v = a0*c0v - a2*s0v;
        float r1v = a1*c1v - a3*s1v;
        float r2v = a2*c0v + a0*s0v;
        float r3v = a3*c1v + a1*s1v;
        if (type==0){
          if (lrow==15) r3v = 1.0f;                 // q[...,-1] = 1
          r0v *= QSCALE; r1v *= QSCALE; r2v *= QSCALE; r3v *= QSCALE;
        } else {
          if (lrow==15) r3v = cum[row];             // k[...,-1] = cumulative_scores
        }
        size_t base = (((size_t)b_*Hh + h)*Tt + (row & 2047))*HDd + lrow;
        dst[base]      = f2bf(r0v);
        dst[base + 16] = f2bf(r1v);
        dst[base + 32] = f2bf(r2v);
        dst[base + 48] = f2bf(r3v);
      }
  } else {
    #pragma unroll
    for (int m=0;m<4;m++)
      #pragma unroll
      for (int q=0;q<4;q++){
        int rl = 64*wr + 16*m + 4*lhi + q;
        int row = mb + rl;
        float vs = __expf(cum[row]);
        sm.v[wc][rl][lrow]      = f2bf((acc[m][0][q]+bz[0])*vs);
        sm.v[wc][rl][16+lrow]   = f2bf((acc[m][1][q]+bz[1])*vs);
        sm.v[wc][rl][32+lrow]   = f2bf((acc[m][2][q]+bz[2])*vs);
        sm.v[wc][rl][48+lrow]   = f2bf((acc[m][3][q]+bz[3])*vs);
      }
    __syncthreads();
    #pragma unroll 8
    for (int i=0;i<64;i++){
      int idx = i*256 + tid;
      int t_l = idx & 127;
      int d   = (idx >> 7) & 63;
      int hh  = idx >> 13;
      VTo[(((size_t)b_*Hh + h0 + hh)*HDd + d)*Tt + tb_ + t_l] = sm.v[hh][t_l][d];
    }
  }
}

// ---------------- 64x128-tile GEMM (fp32 out) for proj ----------------
__global__ __launch_bounds__(256) void k_gemm64(const unsigned short* __restrict__ A,
                                                const unsigned short* __restrict__ Bt,
                                                const float* __restrict__ bias,
                                                float* __restrict__ Cout,
                                                int M, int N, int K){
  __shared__ unsigned short As[64][32];
  __shared__ unsigned short Bs[128][32];
  int mb = blockIdx.y*64, nb = blockIdx.x*128;
  int tid = threadIdx.x;
  int wave = tid>>6, lane = tid&63;
  int wr = wave>>1, wc = wave&1;
  int lrow = lane&15, lhi = lane>>4;
  f32x4 acc[2][4] = {};
  int r0 = tid>>2;
  int c0 = (tid&3)*8;
  const unsigned short* Arow  = A  + (size_t)(mb + r0)*K      + c0;
  const unsigned short* Brow0 = Bt + (size_t)(nb + r0)*K      + c0;
  const unsigned short* Brow1 = Bt + (size_t)(nb + r0 + 64)*K + c0;
#ifdef USE_GLL
  for (int kb=0; kb<K; kb+=32){
    __builtin_amdgcn_global_load_lds((const AS_GLOBAL void*)(Arow + kb),
                                     (AS_LDS void*)&As[r0][c0],    16, 0, 0);
    __builtin_amdgcn_global_load_lds((const AS_GLOBAL void*)(Brow0 + kb),
                                     (AS_LDS void*)&Bs[r0][c0],    16, 0, 0);
    __builtin_amdgcn_global_load_lds((const AS_GLOBAL void*)(Brow1 + kb),
                                     (AS_LDS void*)&Bs[r0+64][c0], 16, 0, 0);
    __syncthreads();
    short8 af[2], bf[4];
    #pragma unroll
    for (int m=0;m<2;m++) af[m] = *(const short8*)&As[32*wr + 16*m + lrow][8*lhi];
    #pragma unroll
    for (int n=0;n<4;n++) bf[n] = *(const short8*)&Bs[64*wc + 16*n + lrow][8*lhi];
    #pragma unroll
    for (int m=0;m<2;m++)
      #pragma unroll
      for (int n=0;n<4;n++)
        acc[m][n] = __builtin_amdgcn_mfma_f32_16x16x32_bf16(af[m], bf[n], acc[m][n], 0,0,0);
    __syncthreads();
  }
#else
  for (int kb=0; kb<K; kb+=32){
    int4 a0 = *(const int4*)(Arow + kb);
    int4 b0 = *(const int4*)(Brow0 + kb);
    int4 b1 = *(const int4*)(Brow1 + kb);
    __syncthreads();
    *(int4*)&As[r0][c0]    = a0;
    *(int4*)&Bs[r0][c0]    = b0;
    *(int4*)&Bs[r0+64][c0] = b1;
    __syncthreads();
    short8 af[2], bf[4];
    #pragma unroll
    for (int m=0;m<2;m++) af[m] = *(const short8*)&As[32*wr + 16*m + lrow][8*lhi];
    #pragma unroll
    for (int n=0;n<4;n++) bf[n] = *(const short8*)&Bs[64*wc + 16*n + lrow][8*lhi];
    #pragma unroll
    for (int m=0;m<2;m++)
      #pragma unroll
      for (int n=0;n<4;n++)
        acc[m][n] = __builtin_amdgcn_mfma_f32_16x16x32_bf16(af[m], bf[n], acc[m][n], 0,0,0);
  }
#endif
  #pragma unroll
  for (int m=0;m<2;m++)
    #pragma unroll
    for (int n=0;n<4;n++)
      #pragma unroll
      for (int q=0;q<4;q++){
        int row = mb + 32*wr + 16*m + 4*lhi + q;
        int col = nb + 64*wc + 16*n + lrow;
        Cout[(size_t)row*N + col] = acc[m][n][q] + bias[col];
      }
}

// ---------------- flash attention v8: split-k + swapped PV (O^T) + exp2 ----------------
// QK swapped -> lane holds S[k][q=lrow]; exp2 (log2e folded into Q scale);
// PV as O^T = V^T * P^T: our S layout IS the B-operand, output lands at q=lrow
// (same as l-partial -> no shuffle broadcast), d contiguous -> 8B packed stores.
__global__ __launch_bounds__(512, 4) void k_attn8(const unsigned short* __restrict__ Q,
                                                  const unsigned short* __restrict__ K,
                                                  const unsigned short* __restrict__ VT,
                                                  unsigned short* __restrict__ Y){
  __shared__ __align__(16) char smem[65536];
  typedef unsigned short (*tile_t)[2][4096];
  tile_t Ks = (tile_t)smem;
  tile_t Vs = (tile_t)(smem + 32768);
  float (*cmb)[64][35] = (float (*)[64][35])smem;

  int bh = blockIdx.y; int b = bh >> 4, h = bh & 15;
  int tid = threadIdx.x;
  int wave = tid>>6, lane = tid&63;
  int wpair = wave & 3, p = wave >> 2;
  int lrow = lane&15, lhi = lane>>4;
  const unsigned short* Qh = Q + (((size_t)b*Hh + h)*Tt)*HDd;
  const unsigned short* Kh = K + (((size_t)b*Hh + h)*Tt)*HDd;
  const unsigned short* Vh = VT + (((size_t)b*Hh + h)*HDd)*Tt;
  int s_ = blockIdx.x;
  int qL0 = 64*s_ + 16*wpair;
  int qH0 = 1984 - 64*s_ + 16*wpair;
  short8 qfL0 = *(const short8*)&Qh[(size_t)(qL0+lrow)*HDd + 8*lhi];
  short8 qfL1 = *(const short8*)&Qh[(size_t)(qL0+lrow)*HDd + 32 + 8*lhi];
  short8 qfH0 = *(const short8*)&Qh[(size_t)(qH0+lrow)*HDd + 8*lhi];
  short8 qfH1 = *(const short8*)&Qh[(size_t)(qH0+lrow)*HDd + 32 + 8*lhi];
  f32x4 oL[4] = {}, oH[4] = {};             // O^T: [jp] -> O[q=lrow][d=16jp+4lhi+r]
  float lsL = 0.0f, lsH = 0.0f;             // per-lane l partial for q=lrow
  int rowL = qL0 + lrow, rowH = qH0 + lrow;
  int ntL = s_ + 1;
  int NTH = 32 - s_;
  int NI  = (NTH + 1) >> 1;

  int kr = tid >> 3, kc = tid & 7;
  int o_ = tid * 16;
  int ksrc = kr*HDd + ((kc ^ (kr&7)) << 3);
  int vsrc = kr*Tt  + ((kc ^ (kr&7)) << 3);

#ifdef USE_GLL
#define STAGE2(bufi, base_) do { \
    __builtin_amdgcn_global_load_lds((const AS_GLOBAL void*)(Kh + (size_t)(base_)*64*HDd + ksrc), \
        (AS_LDS void*)((AS_LDS char*)&Ks[bufi][0][0] + o_), 16, 0, 0); \
    __builtin_amdgcn_global_load_lds((const AS_GLOBAL void*)(Vh + (size_t)(base_)*64 + vsrc), \
        (AS_LDS void*)((AS_LDS char*)&Vs[bufi][0][0] + o_), 16, 0, 0); \
    if ((base_)+1 < NTH){ \
      __builtin_amdgcn_global_load_lds((const AS_GLOBAL void*)(Kh + (size_t)((base_)+1)*64*HDd + ksrc), \
          (AS_LDS void*)((AS_LDS char*)&Ks[bufi][1][0] + o_), 16, 0, 0); \
      __builtin_amdgcn_global_load_lds((const AS_GLOBAL void*)(Vh + (size_t)((base_)+1)*64 + vsrc), \
          (AS_LDS void*)((AS_LDS char*)&Vs[bufi][1][0] + o_), 16, 0, 0); \
    } \
  } while(0)
#else
#define STAGE2(bufi, base_) do { \
    int4 a_ = *(const int4*)(Kh + (size_t)(base_)*64*HDd + ksrc); \
    int4 c_ = *(const int4*)(Vh + (size_t)(base_)*64 + vsrc); \
    *(int4*)((char*)&Ks[bufi][0][0] + o_) = a_; \
    *(int4*)((char*)&Vs[bufi][0][0] + o_) = c_; \
    if ((base_)+1 < NTH){ \
      int4 b_ = *(const int4*)(Kh + (size_t)((base_)+1)*64*HDd + ksrc); \
      int4 d_ = *(const int4*)(Vh + (size_t)((base_)+1)*64 + vsrc); \
      *(int4*)((char*)&Ks[bufi][1][0] + o_) = b_; \
      *(int4*)((char*)&Vs[bufi][1][0] + o_) = d_; \
    } \
  } while(0)
#endif

  STAGE2(0, 0);
  int buf = 0;
  for (int i = 0; i < NI; i++){
    __syncthreads();
    if (i+1 < NI) STAGE2(buf^1, 2*(i+1));
    int kt = 2*i + p;
    if (kt < NTH){
      int k0 = kt*64;
      bool doL = (kt < ntL);
      const unsigned short* Kbase = &Ks[buf][p][0];
      const unsigned short* Vbase = &Vs[buf][p][0];
      f32x4 sL[4] = {}, sH[4] = {};
      __builtin_amdgcn_s_setprio(1);
      #pragma unroll
      for (int j=0;j<4;j++){
        int krow = 16*j + lrow;
        #pragma unroll
        for (int ks=0;ks<2;ks++){
          int dgrp = (4*ks + lhi) ^ (krow&7);
          short8 kf = *(const short8*)&Kbase[krow*64 + dgrp*8];
          sH[j] = __builtin_amdgcn_mfma_f32_16x16x32_bf16(kf, ks ? qfH1 : qfH0, sH[j], 0,0,0);
          if (doL) sL[j] = __builtin_amdgcn_mfma_f32_16x16x32_bf16(kf, ks ? qfL1 : qfL0, sL[j], 0,0,0);
        }
      }
      __builtin_amdgcn_s_setprio(0);
      short4v paH[4], paL[4];
      {
        bool diagH = (k0 + 63 >= qH0);
        #pragma unroll
        for (int j=0;j<4;j++){
          int kbase = k0 + 16*j + 4*lhi;
          float p0 = exp2fast(sH[j][0]);
          float p1 = exp2fast(sH[j][1]);
          float p2 = exp2fast(sH[j][2]);
          float p3 = exp2fast(sH[j][3]);
          if (diagH){
            if (kbase + 0 > rowH) p0 = 0.0f;
            if (kbase + 1 > rowH) p1 = 0.0f;
            if (kbase + 2 > rowH) p2 = 0.0f;
            if (kbase + 3 > rowH) p3 = 0.0f;
          }
          lsH += (p0 + p1) + (p2 + p3);
          union { unsigned int u[2]; short4v v; } pk;
          pk.u[0] = cvtpk_bf16(p0, p1);
          pk.u[1] = cvtpk_bf16(p2, p3);
          paH[j] = pk.v;
        }
      }
      if (doL){
        bool diagL = (k0 + 63 >= qL0);
        #pragma unroll
        for (int j=0;j<4;j++){
          int kbase = k0 + 16*j + 4*lhi;
          float p0 = exp2fast(sL[j][0]);
          float p1 = exp2fast(sL[j][1]);
          float p2 = exp2fast(sL[j][2]);
          float p3 = exp2fast(sL[j][3]);
          if (diagL){
            if (kbase + 0 > rowL) p0 = 0.0f;
            if (kbase + 1 > rowL) p1 = 0.0f;
            if (kbase + 2 > rowL) p2 = 0.0f;
            if (kbase + 3 > rowL) p3 = 0.0f;
          }
          lsL += (p0 + p1) + (p2 + p3);
          union { unsigned int u[2]; short4v v; } pk;
          pk.u[0] = cvtpk_bf16(p0, p1);
          pk.u[1] = cvtpk_bf16(p2, p3);
          paL[j] = pk.v;
        }
      }
      __builtin_amdgcn_s_setprio(1);
      #pragma unroll
      for (int jp=0;jp<4;jp++){
        int vrow = 16*jp + lrow;
        #pragma unroll
        for (int j=0;j<4;j++){
          int byte_in_row = ((((2*j + (lhi>>1)) ^ (vrow&7)) << 4) | ((lhi&1) << 3));
          short4v vf = *(const short4v*)((const char*)&Vbase[vrow*64] + byte_in_row);
          oH[jp] = mfma16(vf, paH[j], oH[jp]);       // A=V^T frag, B=P^T frag
          if (doL) oL[jp] = mfma16(vf, paL[j], oL[jp]);
        }
      }
      __builtin_amdgcn_s_setprio(0);
    }
    buf ^= 1;
  }

  // ---- combine the two k-parities via LDS; reduce + write (p==0 waves) ----
  __syncthreads();
  if (p == 1){
    float* c = &cmb[wpair][lane][0];
    #pragma unroll
    for (int jp=0;jp<4;jp++)
      #pragma unroll
      for (int r=0;r<4;r++){
        c[4*jp+r]    = oL[jp][r];
        c[16+4*jp+r] = oH[jp][r];
      }
    c[32] = lsL; c[33] = lsH;
  }
  __syncthreads();
  if (p == 0){
    const float* c = &cmb[wpair][lane][0];
    #pragma unroll
    for (int jp=0;jp<4;jp++)
      #pragma unroll
      for (int r=0;r<4;r++){
        oL[jp][r] += c[4*jp+r];
        oH[jp][r] += c[16+4*jp+r];
      }
    lsL += c[32]; lsH += c[33];
    lsL += __shfl_xor(lsL, 16); lsL += __shfl_xor(lsL, 32);
    lsH += __shfl_xor(lsH, 16); lsH += __shfl_xor(lsH, 32);
    float invL = 1.0f / lsL, invH = 1.0f / lsH;   // q=lrow: same index as O^T rows
    size_t rbL = ((size_t)b*Tt + qL0 + lrow)*Cc + h*HDd + 4*lhi;
    size_t rbH = ((size_t)b*Tt + qH0 + lrow)*Cc + h*HDd + 4*lhi;
    #pragma unroll
    for (int jp=0;jp<4;jp++){
      unsigned int l0 = cvtpk_bf16(oL[jp][0]*invL, oL[jp][1]*invL);
      unsigned int l1 = cvtpk_bf16(oL[jp][2]*invL, oL[jp][3]*invL);
      unsigned int h0_ = cvtpk_bf16(oH[jp][0]*invH, oH[jp][1]*invH);
      unsigned int h1_ = cvtpk_bf16(oH[jp][2]*invH, oH[jp][3]*invH);
      *(unsigned long long*)&Y[rbL + 16*jp] = (unsigned long long)l0 | ((unsigned long long)l1<<32);
      *(unsigned long long*)&Y[rbH + 16*jp] = (unsigned long long)h0_ | ((unsigned long long)h1_<<32);
    }
  }
#undef STAGE2
}

extern "C" void kernel_launch(void* const* d_in, const int* in_sizes, int n_in,
                              void* d_out, int out_size, void* d_ws, size_t ws_size,
                              hipStream_t stream){
  const float* x     = (const float*)d_in[0];
  const float* cum   = (const float*)d_in[1];
  const int*   tok   = (const int*)d_in[3];
  const float* Wqkv  = (const float*)d_in[4];
  const float* bqkv  = (const float*)d_in[5];
  const float* Wproj = (const float*)d_in[6];
  const float* bproj = (const float*)d_in[7];

  char* ws = (char*)d_ws;
  size_t off = 0;
  auto alloc = [&](size_t bytes)->void*{
    void* p = ws + off; off += (bytes + 255) & ~(size_t)255; return p;
  };
  unsigned short* wqkvT = (unsigned short*)alloc((size_t)3072*1024*2);
  unsigned short* wprojT= (unsigned short*)alloc((size_t)1024*1024*2);
  unsigned short* xb    = (unsigned short*)alloc((size_t)4096*1024*2); // reused as Y
  unsigned short* Qb    = (unsigned short*)alloc((size_t)Bb*Hh*Tt*HDd*2);
  unsigned short* Kb    = (unsigned short*)alloc((size_t)Bb*Hh*Tt*HDd*2);
  unsigned short* VTb   = (unsigned short*)alloc((size_t)Bb*Hh*Tt*HDd*2);
  float* rot            = (float*)alloc((size_t)Bb*Tt*4);
  float* cos_t          = (float*)alloc((size_t)Bb*Tt*32*4);
  float* sin_t          = (float*)alloc((size_t)Bb*Tt*32*4);
  unsigned short* Y     = xb; // alias: xb dead after QKV GEMM

  k_f2b<<<dim3((4096*1024/4 + 255)/256), dim3(256), 0, stream>>>(x, xb, 4096*1024);
  k_transpose_f2b<<<dim3(3072/32, 1024/32), dim3(32,8), 0, stream>>>(Wqkv, wqkvT, 1024, 3072);
  k_transpose_f2b<<<dim3(1024/32, 1024/32), dim3(32,8), 0, stream>>>(Wproj, wprojT, 1024, 1024);
  k_scan<<<dim3(Bb), dim3(1024), 0, stream>>>(tok, rot);
  k_tables<<<dim3(Bb*Tt*32/256), dim3(256), 0, stream>>>(rot, cos_t, sin_t);
  k_gemmQKV<<<dim3(3072/128, 4096/128), dim3(256), 0, stream>>>(xb, wqkvT, bqkv, cos_t, sin_t, cum, Qb, Kb, VTb);
  k_attn8<<<dim3(16, Bb*Hh), dim3(512), 0, stream>>>(Qb, Kb, VTb, Y);
  k_gemm64<<<dim3(1024/128, 4096/64), dim3(256), 0, stream>>>(Y, wprojT, bproj, (float*)d_out, 4096, 1024, 1024);
}

// Round 9
// 123.964 us; speedup vs baseline: 1.7844x; 1.7844x over previous
//
#include <hip/hip_runtime.h>
#include <hip/hip_bf16.h>
#include <math.h>

#define Bb 2
#define Tt 2048
#define Cc 1024
#define Hh 16
#define HDd 64
#define QSCALE 0.18033688011112042f   // 0.125 * log2(e): folds softmax scale + exp->exp2

typedef __attribute__((ext_vector_type(8))) short short8;
typedef __attribute__((ext_vector_type(4))) short short4v;
typedef __attribute__((ext_vector_type(4))) float f32x4;

#if defined(__has_builtin)
#if __has_builtin(__builtin_amdgcn_global_load_lds)
#define USE_GLL 1
#endif
#endif
#define AS_GLOBAL __attribute__((address_space(1)))
#define AS_LDS    __attribute__((address_space(3)))

__device__ __forceinline__ float bf2f(unsigned short u){
  union { unsigned int i; float f; } v; v.i = ((unsigned int)u)<<16; return v.f;
}
__device__ __forceinline__ unsigned short f2bf(float f){
  union { float f; unsigned int i; } v; v.f = f;
  unsigned int x = v.i;
  return (unsigned short)((x + 0x7fffu + ((x>>16)&1u)) >> 16);
}
__device__ __forceinline__ unsigned int cvtpk_bf16(float lo, float hi){
  unsigned int r;
  asm("v_cvt_pk_bf16_f32 %0, %1, %2" : "=v"(r) : "v"(lo), "v"(hi));
  return r;
}
__device__ __forceinline__ float exp2fast(float x){
  float r; asm("v_exp_f32 %0, %1" : "=v"(r) : "v"(x)); return r;
}
__device__ __forceinline__ f32x4 mfma16(short4v a, short4v b, f32x4 c){
#if defined(__has_builtin)
#if __has_builtin(__builtin_amdgcn_mfma_f32_16x16x16_bf16)
  return __builtin_amdgcn_mfma_f32_16x16x16_bf16(a, b, c, 0, 0, 0);
#elif __has_builtin(__builtin_amdgcn_mfma_f32_16x16x16bf16_1k)
  return __builtin_amdgcn_mfma_f32_16x16x16bf16_1k(a, b, c, 0, 0, 0);
#else
  asm("v_mfma_f32_16x16x16_bf16 %0, %1, %2, %3" : "=v"(c) : "v"(a), "v"(b), "0"(c));
  return c;
#endif
#else
  asm("v_mfma_f32_16x16x16_bf16 %0, %1, %2, %3" : "=v"(c) : "v"(a), "v"(b), "0"(c));
  return c;
#endif
}

// ---------------- fp32 -> bf16 convert (vector) ----------------
__global__ __launch_bounds__(256) void k_f2b(const float* __restrict__ in,
                                             unsigned short* __restrict__ out, int n){
  int i = (blockIdx.x*256 + threadIdx.x)*4;
  if (i >= n) return;
  float4 v = *(const float4*)(in + i);
  unsigned long long p = (unsigned long long)f2bf(v.x)
                       | ((unsigned long long)f2bf(v.y)<<16)
                       | ((unsigned long long)f2bf(v.z)<<32)
                       | ((unsigned long long)f2bf(v.w)<<48);
  *(unsigned long long*)(out + i) = p;
}

// ---------------- transpose + convert: W[K][N] f32 -> Wt[N][K] bf16 ----------------
__global__ __launch_bounds__(256) void k_transpose_f2b(const float* __restrict__ in,
                                                       unsigned short* __restrict__ out,
                                                       int K, int N){
  __shared__ float tile[32][33];
  int kb = blockIdx.y*32, nb = blockIdx.x*32;
  int tx = threadIdx.x, ty = threadIdx.y; // (32, 8)
  #pragma unroll
  for (int i=0;i<4;i++)
    tile[ty+i*8][tx] = in[(size_t)(kb+ty+i*8)*N + nb + tx];
  __syncthreads();
  #pragma unroll
  for (int i=0;i<4;i++)
    out[(size_t)(nb+ty+i*8)*K + kb + tx] = f2bf(tile[tx][ty+i*8]);
}

// ---------------- scan: global token counts -> per-batch cumulative rotations ----------------
__global__ __launch_bounds__(1024) void k_scan(const int* __restrict__ tok,
                                               float* __restrict__ rot){
  __shared__ int cnt[2048];
  __shared__ float vals[2048];
  __shared__ float psum[1024];
  int b = blockIdx.x;
  int tid = threadIdx.x;
  cnt[tid] = 0; cnt[tid+1024] = 0;
  __syncthreads();
  // reference's fancy-indexing scatters ALL batches' tokens into every batch's counts
  for (int i = tid; i < Bb*Tt; i += 1024) atomicAdd(&cnt[tok[i]], 1);
  __syncthreads();
  for (int i = tid; i < Tt; i += 1024){
    int idx = tok[b*Tt + i];
    vals[i] = 1.0f / ((float)cnt[idx] + 1e-10f);
  }
  __syncthreads();
  float s0 = vals[2*tid], s1 = vals[2*tid+1];
  psum[tid] = s0 + s1;
  __syncthreads();
  for (int off=1; off<1024; off<<=1){
    float add = (tid>=off) ? psum[tid-off] : 0.0f;
    __syncthreads();
    psum[tid] += add;
    __syncthreads();
  }
  float base = (tid>0) ? psum[tid-1] : 0.0f;
  rot[b*Tt + 2*tid]   = base + s0;
  rot[b*Tt + 2*tid+1] = base + s0 + s1;
}

// ---------------- interleaved (cos,sin) table: cs_t[bt*64 + 2j] = cos, +1 = sin ----------------
__global__ __launch_bounds__(256) void k_tables(const float* __restrict__ rot,
                                                float* __restrict__ cs_t){
  int i = blockIdx.x*256 + threadIdx.x;   // over Bb*Tt*32
  int j = i & 31;
  int bt = i >> 5;
  float invf = exp2f(-(float)j * 0.4152410118609203f);  // 10000^(-j/32)
  float ang = rot[bt] * invf;
  float2 cs = make_float2(cosf(ang), sinf(ang));
  *(float2*)&cs_t[(size_t)bt*64 + 2*j] = cs;
}

// ---------------- fused QKV GEMM (swizzled LDS): rope/overwrite/V-scale epilogue ----------------
// 128x128 tile, VGPR capped at 128 (4 blocks/CU). Staging uses inverse-swizzled
// global source + linear global_load_lds dest; reads XOR group with (row&3):
// spreads a wave's 64 b128 reads over all 8 bank-groups (throughput floor).
// Epilogue: Q/K rope from L2-resident interleaved cs table (partner acc[m][n^2]
// is thread-local); V scaled by exp(cum) + transposed via 4-pass 9KB LDS bounce.
__global__ __launch_bounds__(256, 4) void k_gemmQKV(const unsigned short* __restrict__ A,
                                                    const unsigned short* __restrict__ Bt,
                                                    const float* __restrict__ bias,
                                                    const float* __restrict__ cs_t,
                                                    const float* __restrict__ cum,
                                                    unsigned short* __restrict__ Qo,
                                                    unsigned short* __restrict__ Ko,
                                                    unsigned short* __restrict__ VTo){
  __shared__ union {
    unsigned short ab[2][128][32];   // staging: [0]=A, [1]=B (16 KB)
    unsigned short vb[32][140];      // V transpose bounce, 280B row: 2-way banks (9 KB)
  } sm;
  const int K = 1024, N = 3072;
  int mb = blockIdx.y*128, nb = blockIdx.x*128;
  int tid = threadIdx.x;
  int wave = tid>>6, lane = tid&63;
  int wr = wave>>1, wc = wave&1;
  int lrow = lane&15, lhi = lane>>4;
  f32x4 acc[4][4] = {};
  int r0 = tid>>2;                       // staged row (and row+64)
  int gd = tid&3;                        // dest 16B group
  int gs0 = (gd ^ (r0&3)) << 3;          // swizzled source elem offset (row r0)
  const unsigned short* Arow0 = A  + (size_t)(mb + r0)*K      + gs0;
  const unsigned short* Arow1 = A  + (size_t)(mb + r0 + 64)*K + gs0;
  const unsigned short* Brow0 = Bt + (size_t)(nb + r0)*K      + gs0;
  const unsigned short* Brow1 = Bt + (size_t)(nb + r0 + 64)*K + gs0;
#ifdef USE_GLL
  for (int kb=0; kb<K; kb+=32){
    __builtin_amdgcn_global_load_lds((const AS_GLOBAL void*)(Arow0 + kb),
                                     (AS_LDS void*)&sm.ab[0][r0][gd*8],    16, 0, 0);
    __builtin_amdgcn_global_load_lds((const AS_GLOBAL void*)(Arow1 + kb),
                                     (AS_LDS void*)&sm.ab[0][r0+64][gd*8], 16, 0, 0);
    __builtin_amdgcn_global_load_lds((const AS_GLOBAL void*)(Brow0 + kb),
                                     (AS_LDS void*)&sm.ab[1][r0][gd*8],    16, 0, 0);
    __builtin_amdgcn_global_load_lds((const AS_GLOBAL void*)(Brow1 + kb),
                                     (AS_LDS void*)&sm.ab[1][r0+64][gd*8], 16, 0, 0);
    __syncthreads();
    short8 af[4], bf[4];
    #pragma unroll
    for (int m=0;m<4;m++){
      int R = 64*wr + 16*m + lrow;
      af[m] = *(const short8*)&sm.ab[0][R][(lhi^(R&3))<<3];
    }
    #pragma unroll
    for (int n=0;n<4;n++){
      int R = 64*wc + 16*n + lrow;
      bf[n] = *(const short8*)&sm.ab[1][R][(lhi^(R&3))<<3];
    }
    #pragma unroll
    for (int m=0;m<4;m++)
      #pragma unroll
      for (int n=0;n<4;n++)
        acc[m][n] = __builtin_amdgcn_mfma_f32_16x16x32_bf16(af[m], bf[n], acc[m][n], 0,0,0);
    __syncthreads();
  }
#else
  for (int kb=0; kb<K; kb+=32){
    int4 a0 = *(const int4*)(Arow0 + kb);
    int4 a1 = *(const int4*)(Arow1 + kb);
    int4 b0 = *(const int4*)(Brow0 + kb);
    int4 b1 = *(const int4*)(Brow1 + kb);
    __syncthreads();
    *(int4*)&sm.ab[0][r0][gd*8]    = a0;
    *(int4*)&sm.ab[0][r0+64][gd*8] = a1;
    *(int4*)&sm.ab[1][r0][gd*8]    = b0;
    *(int4*)&sm.ab[1][r0+64][gd*8] = b1;
    __syncthreads();
    short8 af[4], bf[4];
    #pragma unroll
    for (int m=0;m<4;m++){
      int R = 64*wr + 16*m + lrow;
      af[m] = *(const short8*)&sm.ab[0][R][(lhi^(R&3))<<3];
    }
    #pragma unroll
    for (int n=0;n<4;n++){
      int R = 64*wc + 16*n + lrow;
      bf[n] = *(const short8*)&sm.ab[1][R][(lhi^(R&3))<<3];
    }
    #pragma unroll
    for (int m=0;m<4;m++)
      #pragma unroll
      for (int n=0;n<4;n++)
        acc[m][n] = __builtin_amdgcn_mfma_f32_16x16x32_bf16(af[m], bf[n], acc[m][n], 0,0,0);
  }
#endif
  int type = nb >> 10;                       // 0=Q 1=K 2=V
  int h0 = (nb >> 6) & 15;
  int h  = h0 + wc;                          // wave's head (64-col span = 1 head)
  int b_ = mb >> 11;
  int tb_ = mb & 2047;
  float bz[4];
  #pragma unroll
  for (int n=0;n<4;n++) bz[n] = bias[nb + 64*wc + 16*n + lrow];

  if (type < 2){
    unsigned short* dst = (type==0) ? Qo : Ko;
    #pragma unroll
    for (int m=0;m<4;m++)
      #pragma unroll
      for (int q=0;q<4;q++){
        int rl = 64*wr + 16*m + 4*lhi + q;
        int row = mb + rl;
        float2 cs0 = *(const float2*)&cs_t[(size_t)row*64 + 2*lrow];        // j=lrow
        float2 cs1 = *(const float2*)&cs_t[(size_t)row*64 + 32 + 2*lrow];   // j=16+lrow
        float a0 = acc[m][0][q] + bz[0];   // d = lrow
        float a1 = acc[m][1][q] + bz[1];   // d = 16+lrow
        float a2 = acc[m][2][q] + bz[2];   // d = 32+lrow
        float a3 = acc[m][3][q] + bz[3];   // d = 48+lrow
        float r0v = a0*cs0.x - a2*cs0.y;
        float r1v = a1*cs1.x - a3*cs1.y;
        float r2v = a2*cs0.x + a0*cs0.y;
        float r3v = a3*cs1.x + a1*cs1.y;
        if (type==0){
          if (lrow==15) r3v = 1.0f;                 // q[...,-1] = 1 (then scaled)
          r0v *= QSCALE; r1v *= QSCALE; r2v *= QSCALE; r3v *= QSCALE;
        } else {
          if (lrow==15) r3v = cum[row];             // k[...,-1] = cumulative_scores
        }
        size_t base = (((size_t)b_*Hh + h)*Tt + (row & 2047))*HDd + lrow;
        dst[base]      = f2bf(r0v);
        dst[base + 16] = f2bf(r1v);
        dst[base + 32] = f2bf(r2v);
        dst[base + 48] = f2bf(r3v);
      }
  } else {
    // V: scale by exp(cum), transpose via 4 passes of 32 t-rows through 9KB LDS
    for (int pass=0; pass<4; pass++){
      __syncthreads();
      if (wr == (pass>>1)){
        int m0 = 2*(pass&1);
        #pragma unroll
        for (int mm=0; mm<2; mm++){
          int m = m0 + mm;
          #pragma unroll
          for (int q=0;q<4;q++){
            int rl32 = 16*mm + 4*lhi + q;          // row within the 32-row chunk
            float vs = __expf(cum[mb + 32*pass + rl32]);
            sm.vb[rl32][64*wc + lrow]      = f2bf((acc[m][0][q]+bz[0])*vs);
            sm.vb[rl32][64*wc + 16+lrow]   = f2bf((acc[m][1][q]+bz[1])*vs);
            sm.vb[rl32][64*wc + 32+lrow]   = f2bf((acc[m][2][q]+bz[2])*vs);
            sm.vb[rl32][64*wc + 48+lrow]   = f2bf((acc[m][3][q]+bz[3])*vs);
          }
        }
      }
      __syncthreads();
      #pragma unroll
      for (int i=0;i<16;i++){
        int idx = i*256 + tid;
        int t_l = idx & 31;
        int dh  = idx >> 5;          // 0..127
        int d   = dh & 63;
        int hh  = dh >> 6;
        VTo[(((size_t)b_*Hh + h0 + hh)*HDd + d)*Tt + tb_ + 32*pass + t_l] = sm.vb[t_l][64*hh + d];
      }
    }
  }
}

// ---------------- 64x128-tile GEMM (fp32 out, swizzled LDS) for proj ----------------
__global__ __launch_bounds__(256) void k_gemm64(const unsigned short* __restrict__ A,
                                                const unsigned short* __restrict__ Bt,
                                                const float* __restrict__ bias,
                                                float* __restrict__ Cout,
                                                int M, int N, int K){
  __shared__ unsigned short As[64][32];
  __shared__ unsigned short Bs[128][32];
  int mb = blockIdx.y*64, nb = blockIdx.x*128;
  int tid = threadIdx.x;
  int wave = tid>>6, lane = tid&63;
  int wr = wave>>1, wc = wave&1;
  int lrow = lane&15, lhi = lane>>4;
  f32x4 acc[2][4] = {};
  int r0 = tid>>2;
  int gd = tid&3;
  int gs0 = (gd ^ (r0&3)) << 3;
  const unsigned short* Arow  = A  + (size_t)(mb + r0)*K      + gs0;
  const unsigned short* Brow0 = Bt + (size_t)(nb + r0)*K      + gs0;
  const unsigned short* Brow1 = Bt + (size_t)(nb + r0 + 64)*K + gs0;
#ifdef USE_GLL
  for (int kb=0; kb<K; kb+=32){
    __builtin_amdgcn_global_load_lds((const AS_GLOBAL void*)(Arow + kb),
                                     (AS_LDS void*)&As[r0][gd*8],    16, 0, 0);
    __builtin_amdgcn_global_load_lds((const AS_GLOBAL void*)(Brow0 + kb),
                                     (AS_LDS void*)&Bs[r0][gd*8],    16, 0, 0);
    __builtin_amdgcn_global_load_lds((const AS_GLOBAL void*)(Brow1 + kb),
                                     (AS_LDS void*)&Bs[r0+64][gd*8], 16, 0, 0);
    __syncthreads();
    short8 af[2], bf[4];
    #pragma unroll
    for (int m=0;m<2;m++){
      int R = 32*wr + 16*m + lrow;
      af[m] = *(const short8*)&As[R][(lhi^(R&3))<<3];
    }
    #pragma unroll
    for (int n=0;n<4;n++){
      int R = 64*wc + 16*n + lrow;
      bf[n] = *(const short8*)&Bs[R][(lhi^(R&3))<<3];
    }
    #pragma unroll
    for (int m=0;m<2;m++)
      #pragma unroll
      for (int n=0;n<4;n++)
        acc[m][n] = __builtin_amdgcn_mfma_f32_16x16x32_bf16(af[m], bf[n], acc[m][n], 0,0,0);
    __syncthreads();
  }
#else
  for (int kb=0; kb<K; kb+=32){
    int4 a0 = *(const int4*)(Arow + kb);
    int4 b0 = *(const int4*)(Brow0 + kb);
    int4 b1 = *(const int4*)(Brow1 + kb);
    __syncthreads();
    *(int4*)&As[r0][gd*8]    = a0;
    *(int4*)&Bs[r0][gd*8]    = b0;
    *(int4*)&Bs[r0+64][gd*8] = b1;
    __syncthreads();
    short8 af[2], bf[4];
    #pragma unroll
    for (int m=0;m<2;m++){
      int R = 32*wr + 16*m + lrow;
      af[m] = *(const short8*)&As[R][(lhi^(R&3))<<3];
    }
    #pragma unroll
    for (int n=0;n<4;n++){
      int R = 64*wc + 16*n + lrow;
      bf[n] = *(const short8*)&Bs[R][(lhi^(R&3))<<3];
    }
    #pragma unroll
    for (int m=0;m<2;m++)
      #pragma unroll
      for (int n=0;n<4;n++)
        acc[m][n] = __builtin_amdgcn_mfma_f32_16x16x32_bf16(af[m], bf[n], acc[m][n], 0,0,0);
  }
#endif
  #pragma unroll
  for (int m=0;m<2;m++)
    #pragma unroll
    for (int n=0;n<4;n++)
      #pragma unroll
      for (int q=0;q<4;q++){
        int row = mb + 32*wr + 16*m + 4*lhi + q;
        int col = nb + 64*wc + 16*n + lrow;
        Cout[(size_t)row*N + col] = acc[m][n][q] + bias[col];
      }
}

// ---------------- flash attention v8: split-k + swapped PV (O^T) + exp2 ----------------
__global__ __launch_bounds__(512, 4) void k_attn8(const unsigned short* __restrict__ Q,
                                                  const unsigned short* __restrict__ K,
                                                  const unsigned short* __restrict__ VT,
                                                  unsigned short* __restrict__ Y){
  __shared__ __align__(16) char smem[65536];
  typedef unsigned short (*tile_t)[2][4096];
  tile_t Ks = (tile_t)smem;
  tile_t Vs = (tile_t)(smem + 32768);
  float (*cmb)[64][35] = (float (*)[64][35])smem;

  int bh = blockIdx.y; int b = bh >> 4, h = bh & 15;
  int tid = threadIdx.x;
  int wave = tid>>6, lane = tid&63;
  int wpair = wave & 3, p = wave >> 2;
  int lrow = lane&15, lhi = lane>>4;
  const unsigned short* Qh = Q + (((size_t)b*Hh + h)*Tt)*HDd;
  const unsigned short* Kh = K + (((size_t)b*Hh + h)*Tt)*HDd;
  const unsigned short* Vh = VT + (((size_t)b*Hh + h)*HDd)*Tt;
  int s_ = blockIdx.x;
  int qL0 = 64*s_ + 16*wpair;
  int qH0 = 1984 - 64*s_ + 16*wpair;
  short8 qfL0 = *(const short8*)&Qh[(size_t)(qL0+lrow)*HDd + 8*lhi];
  short8 qfL1 = *(const short8*)&Qh[(size_t)(qL0+lrow)*HDd + 32 + 8*lhi];
  short8 qfH0 = *(const short8*)&Qh[(size_t)(qH0+lrow)*HDd + 8*lhi];
  short8 qfH1 = *(const short8*)&Qh[(size_t)(qH0+lrow)*HDd + 32 + 8*lhi];
  f32x4 oL[4] = {}, oH[4] = {};             // O^T: [jp] -> O[q=lrow][d=16jp+4lhi+r]
  float lsL = 0.0f, lsH = 0.0f;
  int rowL = qL0 + lrow, rowH = qH0 + lrow;
  int ntL = s_ + 1;
  int NTH = 32 - s_;
  int NI  = (NTH + 1) >> 1;

  int kr = tid >> 3, kc = tid & 7;
  int o_ = tid * 16;
  int ksrc = kr*HDd + ((kc ^ (kr&7)) << 3);
  int vsrc = kr*Tt  + ((kc ^ (kr&7)) << 3);

#ifdef USE_GLL
#define STAGE2(bufi, base_) do { \
    __builtin_amdgcn_global_load_lds((const AS_GLOBAL void*)(Kh + (size_t)(base_)*64*HDd + ksrc), \
        (AS_LDS void*)((AS_LDS char*)&Ks[bufi][0][0] + o_), 16, 0, 0); \
    __builtin_amdgcn_global_load_lds((const AS_GLOBAL void*)(Vh + (size_t)(base_)*64 + vsrc), \
        (AS_LDS void*)((AS_LDS char*)&Vs[bufi][0][0] + o_), 16, 0, 0); \
    if ((base_)+1 < NTH){ \
      __builtin_amdgcn_global_load_lds((const AS_GLOBAL void*)(Kh + (size_t)((base_)+1)*64*HDd + ksrc), \
          (AS_LDS void*)((AS_LDS char*)&Ks[bufi][1][0] + o_), 16, 0, 0); \
      __builtin_amdgcn_global_load_lds((const AS_GLOBAL void*)(Vh + (size_t)((base_)+1)*64 + vsrc), \
          (AS_LDS void*)((AS_LDS char*)&Vs[bufi][1][0] + o_), 16, 0, 0); \
    } \
  } while(0)
#else
#define STAGE2(bufi, base_) do { \
    int4 a_ = *(const int4*)(Kh + (size_t)(base_)*64*HDd + ksrc); \
    int4 c_ = *(const int4*)(Vh + (size_t)(base_)*64 + vsrc); \
    *(int4*)((char*)&Ks[bufi][0][0] + o_) = a_; \
    *(int4*)((char*)&Vs[bufi][0][0] + o_) = c_; \
    if ((base_)+1 < NTH){ \
      int4 b_ = *(const int4*)(Kh + (size_t)((base_)+1)*64*HDd + ksrc); \
      int4 d_ = *(const int4*)(Vh + (size_t)((base_)+1)*64 + vsrc); \
      *(int4*)((char*)&Ks[bufi][1][0] + o_) = b_; \
      *(int4*)((char*)&Vs[bufi][1][0] + o_) = d_; \
    } \
  } while(0)
#endif

  STAGE2(0, 0);
  int buf = 0;
  for (int i = 0; i < NI; i++){
    __syncthreads();
    if (i+1 < NI) STAGE2(buf^1, 2*(i+1));
    int kt = 2*i + p;
    if (kt < NTH){
      int k0 = kt*64;
      bool doL = (kt < ntL);
      const unsigned short* Kbase = &Ks[buf][p][0];
      const unsigned short* Vbase = &Vs[buf][p][0];
      f32x4 sL[4] = {}, sH[4] = {};
      __builtin_amdgcn_s_setprio(1);
      #pragma unroll
      for (int j=0;j<4;j++){
        int krow = 16*j + lrow;
        #pragma unroll
        for (int ks=0;ks<2;ks++){
          int dgrp = (4*ks + lhi) ^ (krow&7);
          short8 kf = *(const short8*)&Kbase[krow*64 + dgrp*8];
          sH[j] = __builtin_amdgcn_mfma_f32_16x16x32_bf16(kf, ks ? qfH1 : qfH0, sH[j], 0,0,0);
          if (doL) sL[j] = __builtin_amdgcn_mfma_f32_16x16x32_bf16(kf, ks ? qfL1 : qfL0, sL[j], 0,0,0);
        }
      }
      __builtin_amdgcn_s_setprio(0);
      short4v paH[4], paL[4];
      {
        bool diagH = (k0 + 63 >= qH0);
        #pragma unroll
        for (int j=0;j<4;j++){
          int kbase = k0 + 16*j + 4*lhi;
          float p0 = exp2fast(sH[j][0]);
          float p1 = exp2fast(sH[j][1]);
          float p2 = exp2fast(sH[j][2]);
          float p3 = exp2fast(sH[j][3]);
          if (diagH){
            if (kbase + 0 > rowH) p0 = 0.0f;
            if (kbase + 1 > rowH) p1 = 0.0f;
            if (kbase + 2 > rowH) p2 = 0.0f;
            if (kbase + 3 > rowH) p3 = 0.0f;
          }
          lsH += (p0 + p1) + (p2 + p3);
          union { unsigned int u[2]; short4v v; } pk;
          pk.u[0] = cvtpk_bf16(p0, p1);
          pk.u[1] = cvtpk_bf16(p2, p3);
          paH[j] = pk.v;
        }
      }
      if (doL){
        bool diagL = (k0 + 63 >= qL0);
        #pragma unroll
        for (int j=0;j<4;j++){
          int kbase = k0 + 16*j + 4*lhi;
          float p0 = exp2fast(sL[j][0]);
          float p1 = exp2fast(sL[j][1]);
          float p2 = exp2fast(sL[j][2]);
          float p3 = exp2fast(sL[j][3]);
          if (diagL){
            if (kbase + 0 > rowL) p0 = 0.0f;
            if (kbase + 1 > rowL) p1 = 0.0f;
            if (kbase + 2 > rowL) p2 = 0.0f;
            if (kbase + 3 > rowL) p3 = 0.0f;
          }
          lsL += (p0 + p1) + (p2 + p3);
          union { unsigned int u[2]; short4v v; } pk;
          pk.u[0] = cvtpk_bf16(p0, p1);
          pk.u[1] = cvtpk_bf16(p2, p3);
          paL[j] = pk.v;
        }
      }
      __builtin_amdgcn_s_setprio(1);
      #pragma unroll
      for (int jp=0;jp<4;jp++){
        int vrow = 16*jp + lrow;
        #pragma unroll
        for (int j=0;j<4;j++){
          int byte_in_row = ((((2*j + (lhi>>1)) ^ (vrow&7)) << 4) | ((lhi&1) << 3));
          short4v vf = *(const short4v*)((const char*)&Vbase[vrow*64] + byte_in_row);
          oH[jp] = mfma16(vf, paH[j], oH[jp]);       // A=V^T frag, B=P^T frag
          if (doL) oL[jp] = mfma16(vf, paL[j], oL[jp]);
        }
      }
      __builtin_amdgcn_s_setprio(0);
    }
    buf ^= 1;
  }

  __syncthreads();
  if (p == 1){
    float* c = &cmb[wpair][lane][0];
    #pragma unroll
    for (int jp=0;jp<4;jp++)
      #pragma unroll
      for (int r=0;r<4;r++){
        c[4*jp+r]    = oL[jp][r];
        c[16+4*jp+r] = oH[jp][r];
      }
    c[32] = lsL; c[33] = lsH;
  }
  __syncthreads();
  if (p == 0){
    const float* c = &cmb[wpair][lane][0];
    #pragma unroll
    for (int jp=0;jp<4;jp++)
      #pragma unroll
      for (int r=0;r<4;r++){
        oL[jp][r] += c[4*jp+r];
        oH[jp][r] += c[16+4*jp+r];
      }
    lsL += c[32]; lsH += c[33];
    lsL += __shfl_xor(lsL, 16); lsL += __shfl_xor(lsL, 32);
    lsH += __shfl_xor(lsH, 16); lsH += __shfl_xor(lsH, 32);
    float invL = 1.0f / lsL, invH = 1.0f / lsH;
    size_t rbL = ((size_t)b*Tt + qL0 + lrow)*Cc + h*HDd + 4*lhi;
    size_t rbH = ((size_t)b*Tt + qH0 + lrow)*Cc + h*HDd + 4*lhi;
    #pragma unroll
    for (int jp=0;jp<4;jp++){
      unsigned int l0 = cvtpk_bf16(oL[jp][0]*invL, oL[jp][1]*invL);
      unsigned int l1 = cvtpk_bf16(oL[jp][2]*invL, oL[jp][3]*invL);
      unsigned int h0_ = cvtpk_bf16(oH[jp][0]*invH, oH[jp][1]*invH);
      unsigned int h1_ = cvtpk_bf16(oH[jp][2]*invH, oH[jp][3]*invH);
      *(unsigned long long*)&Y[rbL + 16*jp] = (unsigned long long)l0 | ((unsigned long long)l1<<32);
      *(unsigned long long*)&Y[rbH + 16*jp] = (unsigned long long)h0_ | ((unsigned long long)h1_<<32);
    }
  }
#undef STAGE2
}

extern "C" void kernel_launch(void* const* d_in, const int* in_sizes, int n_in,
                              void* d_out, int out_size, void* d_ws, size_t ws_size,
                              hipStream_t stream){
  const float* x     = (const float*)d_in[0];
  const float* cum   = (const float*)d_in[1];
  const int*   tok   = (const int*)d_in[3];
  const float* Wqkv  = (const float*)d_in[4];
  const float* bqkv  = (const float*)d_in[5];
  const float* Wproj = (const float*)d_in[6];
  const float* bproj = (const float*)d_in[7];

  char* ws = (char*)d_ws;
  size_t off = 0;
  auto alloc = [&](size_t bytes)->void*{
    void* p = ws + off; off += (bytes + 255) & ~(size_t)255; return p;
  };
  unsigned short* wqkvT = (unsigned short*)alloc((size_t)3072*1024*2);
  unsigned short* wprojT= (unsigned short*)alloc((size_t)1024*1024*2);
  unsigned short* xb    = (unsigned short*)alloc((size_t)4096*1024*2); // reused as Y
  unsigned short* Qb    = (unsigned short*)alloc((size_t)Bb*Hh*Tt*HDd*2);
  unsigned short* Kb    = (unsigned short*)alloc((size_t)Bb*Hh*Tt*HDd*2);
  unsigned short* VTb   = (unsigned short*)alloc((size_t)Bb*Hh*Tt*HDd*2);
  float* rot            = (float*)alloc((size_t)Bb*Tt*4);
  float* cs_t           = (float*)alloc((size_t)Bb*Tt*64*4);
  unsigned short* Y     = xb; // alias: xb dead after QKV GEMM

  k_f2b<<<dim3((4096*1024/4 + 255)/256), dim3(256), 0, stream>>>(x, xb, 4096*1024);
  k_transpose_f2b<<<dim3(3072/32, 1024/32), dim3(32,8), 0, stream>>>(Wqkv, wqkvT, 1024, 3072);
  k_transpose_f2b<<<dim3(1024/32, 1024/32), dim3(32,8), 0, stream>>>(Wproj, wprojT, 1024, 1024);
  k_scan<<<dim3(Bb), dim3(1024), 0, stream>>>(tok, rot);
  k_tables<<<dim3(Bb*Tt*32/256), dim3(256), 0, stream>>>(rot, cs_t);
  k_gemmQKV<<<dim3(3072/128, 4096/128), dim3(256), 0, stream>>>(xb, wqkvT, bqkv, cs_t, cum, Qb, Kb, VTb);
  k_attn8<<<dim3(16, Bb*Hh), dim3(512), 0, stream>>>(Qb, Kb, VTb, Y);
  k_gemm64<<<dim3(1024/128, 4096/64), dim3(256), 0, stream>>>(Y, wprojT, bproj, (float*)d_out, 4096, 1024, 1024);
}